// Round 1
// baseline (555.733 us; speedup 1.0000x reference)
//
#include <hip/hip_runtime.h>
#include <cstdint>

typedef unsigned short u16;
typedef u16 u16x8 __attribute__((ext_vector_type(8)));
typedef __bf16 bf16x8 __attribute__((ext_vector_type(8)));
typedef float f32x4 __attribute__((ext_vector_type(4)));

// global -> LDS direct copy, 16B per lane. LDS dest is wave-uniform base + lane*16.
#define GLOAD_LDS16(g, l)                                                          \
  __builtin_amdgcn_global_load_lds((const __attribute__((address_space(1))) void*)(g), \
                                   (__attribute__((address_space(3))) void*)(l), 16, 0, 0)

__device__ __forceinline__ u16 f2bf(float f) {
  union { float f; uint32_t u; } v; v.f = f;
  uint32_t u = v.u;
  return (u16)((u + 0x7fffu + ((u >> 16) & 1u)) >> 16);  // RNE
}

// ---------------- f32 -> bf16 conversion, 8 elems/thread ----------------
__global__ __launch_bounds__(256) void cvt_f32_bf16(const float* __restrict__ in,
                                                    u16* __restrict__ out, long n8) {
  long i = (long)blockIdx.x * blockDim.x + threadIdx.x;
  long stride = (long)gridDim.x * blockDim.x;
  for (; i < n8; i += stride) {
    const float4* p = (const float4*)(in + i * 8);
    float4 a = p[0], b = p[1];
    u16x8 o;
    o[0] = f2bf(a.x); o[1] = f2bf(a.y); o[2] = f2bf(a.z); o[3] = f2bf(a.w);
    o[4] = f2bf(b.x); o[5] = f2bf(b.y); o[6] = f2bf(b.z); o[7] = f2bf(b.w);
    *(u16x8*)(out + i * 8) = o;
  }
}

// ---------------- Stage 1: latents[16384,2048] = H @ VT^T  (bf16 MFMA) ----------------
// m97 structure: 128x128 tile, BK=32, 4 waves (2x2), 4x4 16x16x32 frags/wave,
// global_load_lds width=16, 2 barriers per K-step.
template <bool AF32>
__global__ __launch_bounds__(256) void gemm1(const void* __restrict__ Ap,
                                             const u16* __restrict__ B,
                                             u16* __restrict__ Cl) {
  constexpr int K = 4096;
  __shared__ u16 sA[128 * 32];
  __shared__ u16 sB[128 * 32];
  int bid = blockIdx.x;                 // 2048 blocks, 2048 % 8 == 0 -> bijective swizzle
  int swz = (bid & 7) * 256 + (bid >> 3);
  int tn = swz & 15;                    // 16 N-tiles
  int tm = swz >> 4;                    // 128 M-tiles
  int t = threadIdx.x;
  int w = t >> 6, l = t & 63;
  int wr = w >> 1, wc = w & 1;
  int lo = l & 15, hi = l >> 4;

  // staging geometry: instr j of wave w covers LDS chunk (w*2+j)*1024B = rows (w*32+j*16 .. +16)
  const int rS = w * 32 + (l >> 2);     // row for j=0; j=1 adds 16
  const int kS = (l & 3) * 8;           // elem col within BK=32
  const u16* gB = B + (long)(tn * 128 + rS) * K + kS;
  u16* lB = &sB[w * 1024];
  const u16* gA = nullptr;
  u16* lA = &sA[w * 1024];
  const float* fA = nullptr;
  int fr = 0, fk = 0;
  if constexpr (!AF32) {
    gA = (const u16*)Ap + (long)(tm * 128 + rS) * K + kS;
  } else {
    fA = (const float*)Ap;
    fr = t >> 1;                        // 0..127
    fk = (t & 1) * 16;
  }

  f32x4 acc[4][4] = {};
  for (int k0 = 0; k0 < K; k0 += 32) {
    if constexpr (!AF32) {
      GLOAD_LDS16(gA, lA);
      GLOAD_LDS16(gA + 16 * K, lA + 512);
      gA += 32;
    } else {
      const float* src = fA + (long)(tm * 128 + fr) * K + k0 + fk;
      float4 x = *(const float4*)(src);
      float4 y = *(const float4*)(src + 4);
      float4 z = *(const float4*)(src + 8);
      float4 q = *(const float4*)(src + 12);
      u16x8 o1, o2;
      o1[0] = f2bf(x.x); o1[1] = f2bf(x.y); o1[2] = f2bf(x.z); o1[3] = f2bf(x.w);
      o1[4] = f2bf(y.x); o1[5] = f2bf(y.y); o1[6] = f2bf(y.z); o1[7] = f2bf(y.w);
      o2[0] = f2bf(z.x); o2[1] = f2bf(z.y); o2[2] = f2bf(z.z); o2[3] = f2bf(z.w);
      o2[4] = f2bf(q.x); o2[5] = f2bf(q.y); o2[6] = f2bf(q.z); o2[7] = f2bf(q.w);
      *(u16x8*)&sA[fr * 32 + fk] = o1;
      *(u16x8*)&sA[fr * 32 + fk + 8] = o2;
    }
    GLOAD_LDS16(gB, lB);
    GLOAD_LDS16(gB + 16 * K, lB + 512);
    gB += 32;
    __syncthreads();   // compiler drains vmcnt+lgkmcnt before s_barrier

    bf16x8 af[4], bfr[4];
#pragma unroll
    for (int m = 0; m < 4; ++m)
      af[m] = *(const bf16x8*)&sA[(wr * 64 + m * 16 + lo) * 32 + hi * 8];
#pragma unroll
    for (int n = 0; n < 4; ++n)
      bfr[n] = *(const bf16x8*)&sB[(wc * 64 + n * 16 + lo) * 32 + hi * 8];
#pragma unroll
    for (int m = 0; m < 4; ++m)
#pragma unroll
      for (int n = 0; n < 4; ++n)
        acc[m][n] = __builtin_amdgcn_mfma_f32_16x16x32_bf16(af[m], bfr[n], acc[m][n], 0, 0, 0);
    __syncthreads();
  }

  // epilogue: write latents as bf16. C/D map: col = lane&15, row = (lane>>4)*4 + j
#pragma unroll
  for (int m = 0; m < 4; ++m) {
#pragma unroll
    for (int n = 0; n < 4; ++n) {
      int col = tn * 128 + wc * 64 + n * 16 + lo;
      int row = tm * 128 + wr * 64 + m * 16 + hi * 4;
#pragma unroll
      for (int j = 0; j < 4; ++j)
        Cl[(long)(row + j) * 2048 + col] = f2bf(acc[m][n][j]);
    }
  }
}

// ---------------- Stage 2: out[m, g*128+d] = lat[m, g*64..] @ U[g]^T + b[g] ----------------
// Fragments loaded directly from global (tiles L2-resident); no LDS, no barriers.
__global__ __launch_bounds__(256) void stage2(const u16* __restrict__ L,
                                              const u16* __restrict__ U,
                                              const float* __restrict__ Ub,
                                              float* __restrict__ out) {
  int tm = blockIdx.x, g = blockIdx.y;
  int t = threadIdx.x, w = t >> 6, l = t & 63;
  int lo = l & 15, hi = l >> 4;
  const u16* Lb = L + (long)(tm * 128 + w * 32) * 2048 + g * 64;
  const u16* Ug = U + g * 8192;   // [128][64] bf16, K-contiguous
  f32x4 acc[2][8] = {};
#pragma unroll
  for (int ks = 0; ks < 2; ++ks) {
    int ek = ks * 32 + hi * 8;
    bf16x8 a0 = *(const bf16x8*)(Lb + (long)lo * 2048 + ek);
    bf16x8 a1 = *(const bf16x8*)(Lb + (long)(lo + 16) * 2048 + ek);
#pragma unroll
    for (int n = 0; n < 8; ++n) {
      bf16x8 bv = *(const bf16x8*)(Ug + (n * 16 + lo) * 64 + ek);
      acc[0][n] = __builtin_amdgcn_mfma_f32_16x16x32_bf16(a0, bv, acc[0][n], 0, 0, 0);
      acc[1][n] = __builtin_amdgcn_mfma_f32_16x16x32_bf16(a1, bv, acc[1][n], 0, 0, 0);
    }
  }
#pragma unroll
  for (int n = 0; n < 8; ++n) {
    int col = n * 16 + lo;
    float bias = Ub[g * 128 + col];
#pragma unroll
    for (int m = 0; m < 2; ++m) {
      int row = tm * 128 + w * 32 + m * 16 + hi * 4;
#pragma unroll
      for (int j = 0; j < 4; ++j)
        out[(long)(row + j) * 4096 + g * 128 + col] = acc[m][n][j] + bias;
    }
  }
}

extern "C" void kernel_launch(void* const* d_in, const int* in_sizes, int n_in,
                              void* d_out, int out_size, void* d_ws, size_t ws_size,
                              hipStream_t stream) {
  const float* H   = (const float*)d_in[0];   // [4,4096,4096]
  const float* VT  = (const float*)d_in[1];   // [2048,4096]
  const float* Uw  = (const float*)d_in[2];   // [32,128,64]
  const float* Ubp = (const float*)d_in[3];   // [32,128]
  float* out = (float*)d_out;                 // [4,4096,4096]
  const long MH = 67108864L;    // 16384*4096
  const long MV = 8388608L;     // 2048*4096
  const long MU = 262144L;      // 32*128*64
  const long ML = 33554432L;    // 16384*2048
  size_t needFull = (size_t)(MH + MV + MU + ML) * 2;   // ~218.6 MB

  if (ws_size >= needFull) {
    u16* hbf = (u16*)d_ws;
    u16* vbf = hbf + MH;
    u16* ubf = vbf + MV;
    u16* lat = ubf + MU;
    cvt_f32_bf16<<<2048, 256, 0, stream>>>(H, hbf, MH / 8);
    cvt_f32_bf16<<<512, 256, 0, stream>>>(VT, vbf, MV / 8);
    cvt_f32_bf16<<<128, 256, 0, stream>>>(Uw, ubf, MU / 8);
    gemm1<false><<<2048, 256, 0, stream>>>((const void*)hbf, vbf, lat);
    stage2<<<dim3(128, 32), 256, 0, stream>>>(lat, ubf, Ubp, out);
  } else {
    // fallback: no room for bf16 H; convert A on the fly inside the GEMM (reg-staged)
    u16* vbf = (u16*)d_ws;
    u16* ubf = vbf + MV;
    u16* lat = ubf + MU;
    cvt_f32_bf16<<<512, 256, 0, stream>>>(VT, vbf, MV / 8);
    cvt_f32_bf16<<<128, 256, 0, stream>>>(Uw, ubf, MU / 8);
    gemm1<true><<<2048, 256, 0, stream>>>((const void*)H, vbf, lat);
    stage2<<<dim3(128, 32), 256, 0, stream>>>(lat, ubf, Ubp, out);
  }
}

// Round 2
// 458.671 us; speedup vs baseline: 1.2116x; 1.2116x over previous
//
#include <hip/hip_runtime.h>
#include <cstdint>

typedef unsigned short u16;
typedef u16 u16x8 __attribute__((ext_vector_type(8)));
typedef __bf16 bf16x8 __attribute__((ext_vector_type(8)));
typedef float f32x4 __attribute__((ext_vector_type(4)));

#define GLOAD_LDS16(g, l)                                                          \
  __builtin_amdgcn_global_load_lds((const __attribute__((address_space(1))) void*)(g), \
                                   (__attribute__((address_space(3))) void*)(l), 16, 0, 0)

__device__ __forceinline__ u16 f2bf(float f) {
  union { float f; uint32_t u; } v; v.f = f;
  uint32_t u = v.u;
  return (u16)((u + 0x7fffu + ((u >> 16) & 1u)) >> 16);  // RNE
}

// ---------------- f32 -> bf16 conversion, 8 elems/thread ----------------
__global__ __launch_bounds__(256) void cvt_f32_bf16(const float* __restrict__ in,
                                                    u16* __restrict__ out, long n8) {
  long i = (long)blockIdx.x * blockDim.x + threadIdx.x;
  long stride = (long)gridDim.x * blockDim.x;
  for (; i < n8; i += stride) {
    const float4* p = (const float4*)(in + i * 8);
    float4 a = p[0], b = p[1];
    u16x8 o;
    o[0] = f2bf(a.x); o[1] = f2bf(a.y); o[2] = f2bf(a.z); o[3] = f2bf(a.w);
    o[4] = f2bf(b.x); o[5] = f2bf(b.y); o[6] = f2bf(b.z); o[7] = f2bf(b.w);
    *(u16x8*)(out + i * 8) = o;
  }
}

// ============ Stage 1 (fast path): latents = H @ VT^T, 256x256 tile ============
// 8 waves (2M x 4N), BK=32, ring-4 LDS (128 KiB), counted vmcnt(8), per-phase:
// {ds_read subtile | stage 2 gload_lds | barrier | 16 MFMA (setprio) | barrier}.
// LDS swizzle: 16B slot ^= (row>>1)&3, applied read-side + pre-swizzled gload src.
__global__ __launch_bounds__(512, 2) void gemm256(const u16* __restrict__ A,
                                                  const u16* __restrict__ B,
                                                  u16* __restrict__ C) {
  constexpr int K = 4096;
  constexpr int NT = K / 32;          // 128 K-tiles
  __shared__ u16 sm[65536];           // A: 4 bufs @ u16 [b*8192]; B: 4 bufs @ [32768 + b*8192]
  int bid = blockIdx.x;               // 512 blocks, 512 % 8 == 0 -> bijective XCD swizzle
  int swz = (bid & 7) * 64 + (bid >> 3);
  int tn = swz & 7;                   // 8 N-tiles
  int tm = swz >> 3;                  // 64 M-tiles
  int t0 = threadIdx.x;
  int w = t0 >> 6, l = t0 & 63;
  int wr = w >> 2, wc = w & 3;        // 2 M-waves x 4 N-waves
  int lo = l & 15, hi = l >> 4;

  // ---- staging source addresses (pre-swizzled per rule #21) ----
  // lane l of wave w, instr j covers LDS (row = j*128 + w*16 + l/4, slot' = l&3);
  // source fetches global 16B slot (l&3) ^ ((l>>3)&3) of that row.
  int srow = w * 16 + (l >> 2);
  int sslot = (l & 3) ^ ((l >> 3) & 3);
  const u16* gA0 = A + (long)(tm * 256 + srow) * K + sslot * 8;
  const u16* gA1 = gA0 + 128L * K;
  const u16* gB0 = B + (long)(tn * 256 + srow) * K + sslot * 8;
  const u16* gB1 = gB0 + 128L * K;

  // ---- swizzled ds_read base indices (u16 units) ----
  int rslot = (hi ^ ((lo >> 1) & 3)) * 8;
  int aBase = (wr * 128 + lo) * 32 + rslot;            // + qm*2048 + m*512 + b*8192
  int bBase = 32768 + (wc * 64 + lo) * 32 + rslot;     // + n*512 + b*8192

  // ---- prologue: stage tiles 0,1,2 (12 gloads/wave), wait tile 0 ----
#pragma unroll
  for (int pt = 0; pt < 3; ++pt) {
    u16* la = sm + pt * 8192 + w * 512;
    u16* lb = sm + 32768 + pt * 8192 + w * 512;
    GLOAD_LDS16(gA0, la); GLOAD_LDS16(gA1, la + 4096);
    GLOAD_LDS16(gB0, lb); GLOAD_LDS16(gB1, lb + 4096);
    gA0 += 32; gA1 += 32; gB0 += 32; gB1 += 32;
  }
  asm volatile("s_waitcnt vmcnt(8)" ::: "memory");
  __builtin_amdgcn_s_barrier();
  __builtin_amdgcn_sched_barrier(0);

  f32x4 acc[8][4] = {};
  for (int t = 0; t < NT; ++t) {
    int b = t & 3;
    int stb = (t + 3) & 3;            // ring slot for prefetch (freed at end of group t-1)
    bool st = (t + 3) < NT;
    bf16x8 av[4], bv[4];

    // ---- phase 0: reads A(qm=0) + all B; stage next A; MFMA m=0..3 ----
#pragma unroll
    for (int m = 0; m < 4; ++m)
      av[m] = *(const bf16x8*)(sm + b * 8192 + aBase + m * 512);
#pragma unroll
    for (int n = 0; n < 4; ++n)
      bv[n] = *(const bf16x8*)(sm + b * 8192 + bBase + n * 512);
    if (st) {
      u16* la = sm + stb * 8192 + w * 512;
      GLOAD_LDS16(gA0, la); GLOAD_LDS16(gA1, la + 4096);
      gA0 += 32; gA1 += 32;
    }
    __builtin_amdgcn_s_barrier();
    __builtin_amdgcn_sched_barrier(0);
    __builtin_amdgcn_s_setprio(1);
#pragma unroll
    for (int m = 0; m < 4; ++m)
#pragma unroll
      for (int n = 0; n < 4; ++n)
        acc[m][n] = __builtin_amdgcn_mfma_f32_16x16x32_bf16(av[m], bv[n], acc[m][n], 0, 0, 0);
    __builtin_amdgcn_s_setprio(0);
    __builtin_amdgcn_s_barrier();
    __builtin_amdgcn_sched_barrier(0);

    // ---- phase 1: reads A(qm=1); stage next B; MFMA m=4..7; counted vmcnt ----
#pragma unroll
    for (int m = 0; m < 4; ++m)
      av[m] = *(const bf16x8*)(sm + b * 8192 + aBase + 2048 + m * 512);
    if (st) {
      u16* lb = sm + 32768 + stb * 8192 + w * 512;
      GLOAD_LDS16(gB0, lb); GLOAD_LDS16(gB1, lb + 4096);
      gB0 += 32; gB1 += 32;
    }
    __builtin_amdgcn_s_barrier();
    __builtin_amdgcn_sched_barrier(0);
    __builtin_amdgcn_s_setprio(1);
#pragma unroll
    for (int m = 0; m < 4; ++m)
#pragma unroll
      for (int n = 0; n < 4; ++n)
        acc[4 + m][n] = __builtin_amdgcn_mfma_f32_16x16x32_bf16(av[m], bv[n], acc[4 + m][n], 0, 0, 0);
    __builtin_amdgcn_s_setprio(0);
    // tile t+1 must be landed before next group's ds_reads; keep t+2,t+3 in flight
    if (t < NT - 3)       asm volatile("s_waitcnt vmcnt(8)" ::: "memory");
    else if (t == NT - 3) asm volatile("s_waitcnt vmcnt(4)" ::: "memory");
    else if (t == NT - 2) asm volatile("s_waitcnt vmcnt(0)" ::: "memory");
    __builtin_amdgcn_s_barrier();
    __builtin_amdgcn_sched_barrier(0);
  }

  // ---- epilogue: C/D map col = lane&15, row = (lane>>4)*4 + j ----
#pragma unroll
  for (int mq = 0; mq < 8; ++mq) {
#pragma unroll
    for (int n = 0; n < 4; ++n) {
      int col = tn * 256 + wc * 64 + n * 16 + lo;
      long row = tm * 256 + wr * 128 + mq * 16 + hi * 4;
#pragma unroll
      for (int j = 0; j < 4; ++j)
        C[(row + j) * 2048 + col] = f2bf(acc[mq][n][j]);
    }
  }
}

// ============ Stage 1 (fallback, small ws): 128x128 m97-style, A converted in-kernel ============
__global__ __launch_bounds__(256) void gemm1_f32(const float* __restrict__ fA,
                                                 const u16* __restrict__ B,
                                                 u16* __restrict__ Cl) {
  constexpr int K = 4096;
  __shared__ u16 sA[128 * 32];
  __shared__ u16 sB[128 * 32];
  int bid = blockIdx.x;
  int swz = (bid & 7) * 256 + (bid >> 3);
  int tn = swz & 15;
  int tm = swz >> 4;
  int t = threadIdx.x;
  int w = t >> 6, l = t & 63;
  int wr = w >> 1, wc = w & 1;
  int lo = l & 15, hi = l >> 4;
  const int rS = w * 32 + (l >> 2);
  const int kS = (l & 3) * 8;
  const u16* gB = B + (long)(tn * 128 + rS) * K + kS;
  u16* lB = &sB[w * 1024];
  int fr = t >> 1, fk = (t & 1) * 16;

  f32x4 acc[4][4] = {};
  for (int k0 = 0; k0 < K; k0 += 32) {
    const float* src = fA + (long)(tm * 128 + fr) * K + k0 + fk;
    float4 x = *(const float4*)(src);
    float4 y = *(const float4*)(src + 4);
    float4 z = *(const float4*)(src + 8);
    float4 q = *(const float4*)(src + 12);
    u16x8 o1, o2;
    o1[0] = f2bf(x.x); o1[1] = f2bf(x.y); o1[2] = f2bf(x.z); o1[3] = f2bf(x.w);
    o1[4] = f2bf(y.x); o1[5] = f2bf(y.y); o1[6] = f2bf(y.z); o1[7] = f2bf(y.w);
    o2[0] = f2bf(z.x); o2[1] = f2bf(z.y); o2[2] = f2bf(z.z); o2[3] = f2bf(z.w);
    o2[4] = f2bf(q.x); o2[5] = f2bf(q.y); o2[6] = f2bf(q.z); o2[7] = f2bf(q.w);
    *(u16x8*)&sA[fr * 32 + fk] = o1;
    *(u16x8*)&sA[fr * 32 + fk + 8] = o2;
    GLOAD_LDS16(gB, lB);
    GLOAD_LDS16(gB + 16 * K, lB + 512);
    gB += 32;
    __syncthreads();
    bf16x8 af[4], bfr[4];
#pragma unroll
    for (int m = 0; m < 4; ++m)
      af[m] = *(const bf16x8*)&sA[(wr * 64 + m * 16 + lo) * 32 + hi * 8];
#pragma unroll
    for (int n = 0; n < 4; ++n)
      bfr[n] = *(const bf16x8*)&sB[(wc * 64 + n * 16 + lo) * 32 + hi * 8];
#pragma unroll
    for (int m = 0; m < 4; ++m)
#pragma unroll
      for (int n = 0; n < 4; ++n)
        acc[m][n] = __builtin_amdgcn_mfma_f32_16x16x32_bf16(af[m], bfr[n], acc[m][n], 0, 0, 0);
    __syncthreads();
  }
#pragma unroll
  for (int m = 0; m < 4; ++m)
#pragma unroll
    for (int n = 0; n < 4; ++n) {
      int col = tn * 128 + wc * 64 + n * 16 + lo;
      int row = tm * 128 + wr * 64 + m * 16 + hi * 4;
#pragma unroll
      for (int j = 0; j < 4; ++j)
        Cl[(long)(row + j) * 2048 + col] = f2bf(acc[m][n][j]);
    }
}

// ---------------- Stage 2: out[m, g*128+d] = lat[m, g*64..] @ U[g]^T + b[g] ----------------
__global__ __launch_bounds__(256) void stage2(const u16* __restrict__ L,
                                              const u16* __restrict__ U,
                                              const float* __restrict__ Ub,
                                              float* __restrict__ out) {
  int tm = blockIdx.x, g = blockIdx.y;
  int t = threadIdx.x, w = t >> 6, l = t & 63;
  int lo = l & 15, hi = l >> 4;
  const u16* Lb = L + (long)(tm * 128 + w * 32) * 2048 + g * 64;
  const u16* Ug = U + g * 8192;   // [128][64] bf16, K-contiguous
  f32x4 acc[2][8] = {};
#pragma unroll
  for (int ks = 0; ks < 2; ++ks) {
    int ek = ks * 32 + hi * 8;
    bf16x8 a0 = *(const bf16x8*)(Lb + (long)lo * 2048 + ek);
    bf16x8 a1 = *(const bf16x8*)(Lb + (long)(lo + 16) * 2048 + ek);
#pragma unroll
    for (int n = 0; n < 8; ++n) {
      bf16x8 bv = *(const bf16x8*)(Ug + (n * 16 + lo) * 64 + ek);
      acc[0][n] = __builtin_amdgcn_mfma_f32_16x16x32_bf16(a0, bv, acc[0][n], 0, 0, 0);
      acc[1][n] = __builtin_amdgcn_mfma_f32_16x16x32_bf16(a1, bv, acc[1][n], 0, 0, 0);
    }
  }
#pragma unroll
  for (int n = 0; n < 8; ++n) {
    int col = n * 16 + lo;
    float bias = Ub[g * 128 + col];
#pragma unroll
    for (int m = 0; m < 2; ++m) {
      int row = tm * 128 + w * 32 + m * 16 + hi * 4;
#pragma unroll
      for (int j = 0; j < 4; ++j)
        out[(long)(row + j) * 4096 + g * 128 + col] = acc[m][n][j] + bias;
    }
  }
}

extern "C" void kernel_launch(void* const* d_in, const int* in_sizes, int n_in,
                              void* d_out, int out_size, void* d_ws, size_t ws_size,
                              hipStream_t stream) {
  const float* H   = (const float*)d_in[0];   // [4,4096,4096]
  const float* VT  = (const float*)d_in[1];   // [2048,4096]
  const float* Uw  = (const float*)d_in[2];   // [32,128,64]
  const float* Ubp = (const float*)d_in[3];   // [32,128]
  float* out = (float*)d_out;                 // [4,4096,4096]
  const long MH = 67108864L;    // 16384*4096
  const long MV = 8388608L;     // 2048*4096
  const long MU = 262144L;      // 32*128*64
  const long ML = 33554432L;    // 16384*2048
  size_t needFull = (size_t)(MH + MV + MU + ML) * 2;   // ~218.6 MB

  if (ws_size >= needFull) {
    u16* hbf = (u16*)d_ws;
    u16* vbf = hbf + MH;
    u16* ubf = vbf + MV;
    u16* lat = ubf + MU;
    cvt_f32_bf16<<<2048, 256, 0, stream>>>(H, hbf, MH / 8);
    cvt_f32_bf16<<<512, 256, 0, stream>>>(VT, vbf, MV / 8);
    cvt_f32_bf16<<<128, 256, 0, stream>>>(Uw, ubf, MU / 8);
    gemm256<<<512, 512, 0, stream>>>(hbf, vbf, lat);
    stage2<<<dim3(128, 32), 256, 0, stream>>>(lat, ubf, Ubp, out);
  } else {
    u16* vbf = (u16*)d_ws;
    u16* ubf = vbf + MV;
    u16* lat = ubf + MU;
    cvt_f32_bf16<<<512, 256, 0, stream>>>(VT, vbf, MV / 8);
    cvt_f32_bf16<<<128, 256, 0, stream>>>(Uw, ubf, MU / 8);
    gemm1_f32<<<2048, 256, 0, stream>>>(H, vbf, lat);
    stage2<<<dim3(128, 32), 256, 0, stream>>>(lat, ubf, Ubp, out);
  }
}